// Round 1
// baseline (267.558 us; speedup 1.0000x reference)
//
#include <hip/hip_runtime.h>
#include <hip/hip_bf16.h>
#include <stdint.h>

typedef float  f32x4 __attribute__((ext_vector_type(4)));
typedef short  s16x8 __attribute__((ext_vector_type(8)));

#define GLOAD_LDS16(g, l)                                                          \
  __builtin_amdgcn_global_load_lds(                                                \
      (const __attribute__((address_space(1))) unsigned int*)(g),                  \
      (__attribute__((address_space(3))) unsigned int*)(l), 16, 0, 0)

static __device__ __forceinline__ unsigned short f2bf(float f) {
  union { float f; unsigned u; } v; v.f = f;
  unsigned r = v.u + 0x7fffu + ((v.u >> 16) & 1u);   // RNE
  return (unsigned short)(r >> 16);
}

static __device__ __forceinline__ int swz_e(int r) { return ((r & 3) ^ ((r >> 2) & 1)); }
// byte offset of 16B chunk c (0..3) of row r in an LDS tile [128 rows][32 bf16] (64B rows)
static __device__ __forceinline__ int swz_byte(int r, int c) {
  return r * 64 + (((c ^ swz_e(r)) & 3) << 4);
}

// ---------------- pre-pass: Wt[k-1][col][d] = bf16(W[k][d][col]), k = 1..8 ----------------
__global__ __launch_bounds__(256) void transpose_w(const float* __restrict__ w,
                                                   short* __restrict__ wt) {
  __shared__ unsigned int lds[64 * 33];
  const int t = threadIdx.x;
  const int bid = blockIdx.x;
  const int kb = bid >> 8;            // 0..7  (k = kb+1)
  const int db = (bid >> 4) & 15;
  const int cb = bid & 15;
  const int d0 = db * 64, c0 = cb * 64;
  const float* src = w + (size_t)(kb + 1) * 1048576 + (size_t)d0 * 1024 + c0;
  #pragma unroll
  for (int p = 0; p < 4; ++p) {
    int dl = p * 16 + (t >> 4);
    int c4 = (t & 15) * 4;
    f32x4 f = *(const f32x4*)(src + (size_t)dl * 1024 + c4);
    unsigned lo = (unsigned)f2bf(f.x) | ((unsigned)f2bf(f.y) << 16);
    unsigned hi = (unsigned)f2bf(f.z) | ((unsigned)f2bf(f.w) << 16);
    lds[dl * 33 + (t & 15) * 2]     = lo;
    lds[dl * 33 + (t & 15) * 2 + 1] = hi;
  }
  __syncthreads();
  const int col = t >> 2;   // 0..63
  const int dc  = t & 3;    // 16-d chunk
  union { unsigned short u[8]; s16x8 v; } o0, o1;
  #pragma unroll
  for (int j = 0; j < 16; ++j) {
    int dl = dc * 16 + j;
    unsigned word = lds[dl * 33 + (col >> 1)];
    unsigned short e = (col & 1) ? (unsigned short)(word >> 16) : (unsigned short)(word & 0xffffu);
    if (j < 8) o0.u[j] = e; else o1.u[j - 8] = e;
  }
  short* dst = wt + ((size_t)(kb * 1024 + c0 + col) * 1024 + d0 + dc * 16);
  *(s16x8*)dst       = o0.v;
  *(s16x8*)(dst + 8) = o1.v;
}

// ---------------- bias[c] = sum_d W[0][d][c]  (the T_0 @ W_0 term) ----------------
__global__ __launch_bounds__(256) void bias_k(const float* __restrict__ w,
                                              float* __restrict__ b) {
  int c = blockIdx.x * 256 + threadIdx.x;
  float s = 0.f;
  for (int d = 0; d < 1024; ++d) s += w[(size_t)d * 1024 + c];
  b[c] = s;
}

// ---------------- fused Chebyshev GEMM ----------------
// 128x128 tile, 4 waves (2x2), 16x16x32 bf16 MFMA, BK=32.
template <bool USE_WS>
__global__ __launch_bounds__(256, 2) void cheb_gemm(
    const float* __restrict__ x, const float* __restrict__ w,
    const short* __restrict__ wt, const float* __restrict__ bias,
    float* __restrict__ out) {
  __shared__ short Asm[4096];   // [128 rows][32 dd] bf16, swizzled
  __shared__ short Bsm[4096];   // [128 cols][32 dd] bf16, swizzled

  const int tid  = threadIdx.x;
  const int lane = tid & 63;
  const int wid  = tid >> 6;
  const int mb = blockIdx.x >> 3, nb = blockIdx.x & 7;
  const int rowbase = mb * 128, colbase = nb * 128;
  const int wr = wid >> 1, wc = wid & 1;

  f32x4 acc[4][4];
  #pragma unroll
  for (int m = 0; m < 4; ++m)
    #pragma unroll
    for (int n = 0; n < 4; ++n) acc[m][n] = (f32x4){0.f, 0.f, 0.f, 0.f};

  // A-tile write slots (this thread generates rows arow, dd = ahalf*16..+15)
  const int arow = tid & 127, ahalf = tid >> 7;
  char* const aw0 = (char*)Asm + swz_byte(arow, ahalf * 2);
  char* const aw1 = (char*)Asm + swz_byte(arow, ahalf * 2 + 1);

  // fragment read offsets
  const int la = lane & 15, lg = lane >> 4;
  int abyte[4], bbyte[4];
  #pragma unroll
  for (int m = 0; m < 4; ++m) abyte[m] = swz_byte(wr * 64 + m * 16 + la, lg);
  #pragma unroll
  for (int n = 0; n < 4; ++n) bbyte[n] = swz_byte(wc * 64 + n * 16 + la, lg);

  // PATH A: per-lane pre-swizzled global source pieces for global_load_lds
  int bcol[2], bgoff[2];
  #pragma unroll
  for (int j = 0; j < 2; ++j) {
    int o     = (wid * 2 + j) * 1024 + lane * 16;   // linear LDS byte this lane fills
    int col_l = o >> 6;
    int g     = ((o >> 4) & 3) ^ swz_e(col_l);      // which 8-d chunk must land here
    bcol[j]  = col_l;
    bgoff[j] = g * 8;                               // shorts
  }

  const float* xp = x + (size_t)(rowbase + arow) * 1024 + ahalf * 16;

  for (int d0 = 0; d0 < 1024; d0 += 32) {
    float xv[16];
    #pragma unroll
    for (int j = 0; j < 4; ++j) {
      f32x4 f = *(const f32x4*)(xp + d0 + j * 4);
      xv[j * 4 + 0] = f.x; xv[j * 4 + 1] = f.y; xv[j * 4 + 2] = f.z; xv[j * 4 + 3] = f.w;
    }
    float p1[16], p2[16], x2[16];
    #pragma unroll
    for (int i = 0; i < 16; ++i) { p2[i] = 1.f; p1[i] = xv[i]; x2[i] = xv[i] + xv[i]; }

    const int K0 = USE_WS ? 1 : 0;
    #pragma unroll
    for (int k = K0; k <= 8; ++k) {
      union { unsigned short u[8]; s16x8 v; } pa, pb;
      if (k == 0) {
        #pragma unroll
        for (int i = 0; i < 8; ++i) { pa.u[i] = 0x3f80; pb.u[i] = 0x3f80; }
      } else if (k == 1) {
        #pragma unroll
        for (int i = 0; i < 8; ++i) { pa.u[i] = f2bf(p1[i]); pb.u[i] = f2bf(p1[i + 8]); }
      } else {
        #pragma unroll
        for (int i = 0; i < 16; ++i) {
          float cur = fmaf(x2[i], p1[i], -p2[i]);
          p2[i] = p1[i]; p1[i] = cur;
          unsigned short e = f2bf(cur);
          if (i < 8) pa.u[i] = e; else pb.u[i - 8] = e;
        }
      }

      __syncthreads();                 // previous step's frag reads done
      *(s16x8*)aw0 = pa.v;
      *(s16x8*)aw1 = pb.v;

      if (USE_WS) {
        const short* wk = wt + (size_t)(k - 1) * 1048576;
        #pragma unroll
        for (int j = 0; j < 2; ++j) {
          const short* g = wk + (size_t)(colbase + bcol[j]) * 1024 + d0 + bgoff[j];
          GLOAD_LDS16(g, (char*)Bsm + (wid * 2 + j) * 1024);
        }
      } else {
        const int dd = tid & 31, cg = tid >> 5;
        const float* wsrc = w + (size_t)k * 1048576 + (size_t)(d0 + dd) * 1024 + colbase + cg * 4;
        #pragma unroll
        for (int p = 0; p < 4; ++p) {
          f32x4 f = *(const f32x4*)(wsrc + p * 32);
          #pragma unroll
          for (int jj = 0; jj < 4; ++jj) {
            int col = cg * 4 + p * 32 + jj;
            int byt = col * 64 + ((dd & 7) << 1) + ((((dd >> 3) ^ swz_e(col)) & 3) << 4);
            float vv = (jj == 0) ? f.x : (jj == 1) ? f.y : (jj == 2) ? f.z : f.w;
            *(unsigned short*)((char*)Bsm + byt) = f2bf(vv);
          }
        }
      }
      __syncthreads();                 // A/B tiles ready (compiler drains vmcnt/lgkmcnt)

      s16x8 af[4], bfr[4];
      #pragma unroll
      for (int m = 0; m < 4; ++m) af[m] = *(const s16x8*)((char*)Asm + abyte[m]);
      #pragma unroll
      for (int n = 0; n < 4; ++n) bfr[n] = *(const s16x8*)((char*)Bsm + bbyte[n]);
      #pragma unroll
      for (int m = 0; m < 4; ++m)
        #pragma unroll
        for (int n = 0; n < 4; ++n)
          acc[m][n] = __builtin_amdgcn_mfma_f32_16x16x32_bf16(af[m], bfr[n], acc[m][n], 0, 0, 0);
    }
  }

  // epilogue: C = acc + bias(col)
  float bv[4];
  #pragma unroll
  for (int n = 0; n < 4; ++n)
    bv[n] = USE_WS ? bias[colbase + wc * 64 + n * 16 + la] : 0.f;
  #pragma unroll
  for (int m = 0; m < 4; ++m) {
    int r0 = rowbase + wr * 64 + m * 16 + (lg << 2);
    #pragma unroll
    for (int n = 0; n < 4; ++n) {
      int c = colbase + wc * 64 + n * 16 + la;
      #pragma unroll
      for (int j = 0; j < 4; ++j)
        out[(size_t)(r0 + j) * 1024 + c] = acc[m][n][j] + bv[n];
    }
  }
}

extern "C" void kernel_launch(void* const* d_in, const int* in_sizes, int n_in,
                              void* d_out, int out_size, void* d_ws, size_t ws_size,
                              hipStream_t stream) {
  const float* x = (const float*)d_in[0];
  const float* w = (const float*)d_in[1];
  float* out = (float*)d_out;

  const size_t WT_BYTES = (size_t)8 * 1024 * 1024 * 2;   // 16 MiB: Wt[8][1024][1024] bf16
  const bool use_ws = ws_size >= WT_BYTES + 4096;

  if (use_ws) {
    short* wt   = (short*)d_ws;
    float* bias = (float*)((char*)d_ws + WT_BYTES);
    transpose_w<<<2048, 256, 0, stream>>>(w, wt);
    bias_k<<<4, 256, 0, stream>>>(w, bias);
    cheb_gemm<true><<<512, 256, 0, stream>>>(x, w, wt, bias, out);
  } else {
    cheb_gemm<false><<<512, 256, 0, stream>>>(x, w, nullptr, nullptr, out);
  }
}

// Round 2
// 205.587 us; speedup vs baseline: 1.3014x; 1.3014x over previous
//
#include <hip/hip_runtime.h>
#include <hip/hip_bf16.h>
#include <stdint.h>

typedef float  f32x4 __attribute__((ext_vector_type(4)));
typedef short  s16x8 __attribute__((ext_vector_type(8)));

#define GLOAD_LDS16(g, l)                                                          \
  __builtin_amdgcn_global_load_lds(                                               \
      (const __attribute__((address_space(1))) unsigned int*)(g),                 \
      (__attribute__((address_space(3))) unsigned int*)(l), 16, 0, 0)

static __device__ __forceinline__ unsigned short f2bf(float f) {
  union { __hip_bfloat16 b; unsigned short s; } cv;
  cv.b = __float2bfloat16(f);          // RNE; lets compiler pair into v_cvt_pk_bf16_f32
  return cv.s;
}

static __device__ __forceinline__ int swz_e(int r) { return ((r & 3) ^ ((r >> 2) & 1)); }
// byte offset of 16B chunk c (0..3) of row r in an LDS tile [R rows][32 bf16] (64B rows)
static __device__ __forceinline__ int swz_byte(int r, int c) {
  return r * 64 + (((c ^ swz_e(r)) & 3) << 4);
}

// ---------------- pre-pass: Wt[k-1][col][d] = bf16(W[k][d][col]), k = 1..8 ----------------
__global__ __launch_bounds__(256) void transpose_w(const float* __restrict__ w,
                                                   short* __restrict__ wt) {
  __shared__ unsigned int lds[64 * 33];
  const int t = threadIdx.x;
  const int bid = blockIdx.x;
  const int kb = bid >> 8;            // 0..7  (k = kb+1)
  const int db = (bid >> 4) & 15;
  const int cb = bid & 15;
  const int d0 = db * 64, c0 = cb * 64;
  const float* src = w + (size_t)(kb + 1) * 1048576 + (size_t)d0 * 1024 + c0;
  #pragma unroll
  for (int p = 0; p < 4; ++p) {
    int dl = p * 16 + (t >> 4);
    int c4 = (t & 15) * 4;
    f32x4 f = *(const f32x4*)(src + (size_t)dl * 1024 + c4);
    unsigned lo = (unsigned)f2bf(f.x) | ((unsigned)f2bf(f.y) << 16);
    unsigned hi = (unsigned)f2bf(f.z) | ((unsigned)f2bf(f.w) << 16);
    lds[dl * 33 + (t & 15) * 2]     = lo;
    lds[dl * 33 + (t & 15) * 2 + 1] = hi;
  }
  __syncthreads();
  const int col = t >> 2;   // 0..63
  const int dc  = t & 3;    // 16-d chunk
  union { unsigned short u[8]; s16x8 v; } o0, o1;
  #pragma unroll
  for (int j = 0; j < 16; ++j) {
    int dl = dc * 16 + j;
    unsigned word = lds[dl * 33 + (col >> 1)];
    unsigned short e = (col & 1) ? (unsigned short)(word >> 16) : (unsigned short)(word & 0xffffu);
    if (j < 8) o0.u[j] = e; else o1.u[j - 8] = e;
  }
  short* dst = wt + ((size_t)(kb * 1024 + c0 + col) * 1024 + d0 + dc * 16);
  *(s16x8*)dst       = o0.v;
  *(s16x8*)(dst + 8) = o1.v;
}

// ---------------- bias[c] = sum_d W[0][d][c]  (the T_0 @ W_0 term) ----------------
__global__ __launch_bounds__(256) void bias_k(const float* __restrict__ w,
                                              float* __restrict__ b) {
  __shared__ float red[256];
  const int t = threadIdx.x;
  const int col = blockIdx.x * 64 + (t & 63);
  const int seg = t >> 6;
  float s = 0.f;
  const float* p = w + (size_t)(seg * 256) * 1024 + col;
  for (int d = 0; d < 256; ++d) s += p[(size_t)d * 1024];
  red[t] = s;
  __syncthreads();
  if (t < 64) b[col] = red[t] + red[t + 64] + red[t + 128] + red[t + 192];
}

// ---------------- out init: out[r][c] = bias[c] (or 0) ----------------
__global__ __launch_bounds__(256) void init_out(const float* __restrict__ bias,
                                                float* __restrict__ out, int has_bias) {
  const size_t i = (size_t)blockIdx.x * 256 + threadIdx.x;
  const int c = (int)((i * 4) & 1023);
  f32x4 v = has_bias ? *(const f32x4*)(bias + c) : (f32x4){0.f, 0.f, 0.f, 0.f};
  *(f32x4*)(out + i * 4) = v;
}

// ---------------- fused Chebyshev GEMM ----------------
// block 128M x 256N, split-K x2 (d-halves), 4 waves (2x2), wave tile 64x128,
// BK=32, double-buffered LDS, ONE barrier per step, atomicAdd f32 epilogue.
template <bool USE_WS>
__global__ __launch_bounds__(256, 2) void cheb_gemm(
    const float* __restrict__ x, const float* __restrict__ w,
    const short* __restrict__ wt, float* __restrict__ out) {
  constexpr int KP = USE_WS ? 8 : 9;      // k-steps per d0 strip
  constexpr int NSTEP = 16 * KP;          // 16 strips of 32 dims (one d-half)
  __shared__ short Asm[2][4096];          // [buf][128 rows][32 dims] swizzled
  __shared__ short Bsm[2][8192];          // [buf][256 cols][32 dims] swizzled

  const int tid = threadIdx.x, lane = tid & 63, wid = tid >> 6;
  // XCD-aware swizzle (grid 512, 512%8==0 -> bijective)
  const int bid = blockIdx.x;
  const int swz = (bid & 7) * 64 + (bid >> 3);
  const int kb = swz & 1;
  const int t2 = swz >> 1;                 // 0..255
  const int mb = t2 & 63, nb = t2 >> 6;
  const int rowbase = mb * 128, colbase = nb * 256;
  const int kbase = kb * 512;
  const int wr = wid >> 1, wc = wid & 1;
  const int la = lane & 15, lg = lane >> 4;

  f32x4 acc[4][8];
  #pragma unroll
  for (int m = 0; m < 4; ++m)
    #pragma unroll
    for (int n = 0; n < 8; ++n) acc[m][n] = (f32x4){0.f, 0.f, 0.f, 0.f};

  // A generation: thread owns row (tid&127), dims h*16..h*16+15 of the strip
  const int arow = tid & 127, h = tid >> 7;
  const int aw0 = swz_byte(arow, 2 * h), aw1 = swz_byte(arow, 2 * h + 1);

  int abyte[4], bbyte[8];
  #pragma unroll
  for (int m = 0; m < 4; ++m) abyte[m] = swz_byte(wr * 64 + m * 16 + la, lg);
  #pragma unroll
  for (int n = 0; n < 8; ++n) bbyte[n] = swz_byte(wc * 128 + n * 16 + la, lg);

  // pre-swizzled per-lane global source for B global_load_lds (4 instrs/wave)
  int bcol[4], bgoff[4];
  #pragma unroll
  for (int j = 0; j < 4; ++j) {
    bcol[j]  = (wid * 4 + j) * 16 + (lane >> 2);
    bgoff[j] = ((lane & 3) ^ swz_e(bcol[j])) * 8;
  }

  float x2[16], p1[16], p2[16];
  s16x8 na0, na1;

#define GEN(NS)                                                                   \
  { const int r_ = (NS) % KP;                                                     \
    union { unsigned short u[8]; s16x8 v; } o0_, o1_;                             \
    if (r_ == 0) {                                                                \
      const int d0n = kbase + ((NS) / KP) * 32;                                   \
      const float* xg = x + (size_t)(rowbase + arow) * 1024 + d0n + h * 16;       \
      _Pragma("unroll")                                                           \
      for (int j_ = 0; j_ < 4; ++j_) {                                            \
        f32x4 f_ = *(const f32x4*)(xg + j_ * 4);                                  \
        _Pragma("unroll")                                                         \
        for (int q_ = 0; q_ < 4; ++q_) {                                          \
          float xv_ = f_[q_]; int i_ = j_ * 4 + q_;                               \
          x2[i_] = xv_ + xv_; p1[i_] = xv_; p2[i_] = 1.f;                         \
        }                                                                         \
      }                                                                           \
      if (USE_WS) {                                                               \
        _Pragma("unroll")                                                         \
        for (int i_ = 0; i_ < 8; ++i_) { o0_.u[i_] = f2bf(p1[i_]); o1_.u[i_] = f2bf(p1[i_ + 8]); } \
      } else {                                                                    \
        _Pragma("unroll")                                                         \
        for (int i_ = 0; i_ < 8; ++i_) { o0_.u[i_] = 0x3f80; o1_.u[i_] = 0x3f80; } \
      }                                                                           \
    } else if (!USE_WS && r_ == 1) {                                              \
      _Pragma("unroll")                                                           \
      for (int i_ = 0; i_ < 8; ++i_) { o0_.u[i_] = f2bf(p1[i_]); o1_.u[i_] = f2bf(p1[i_ + 8]); } \
    } else {                                                                      \
      _Pragma("unroll")                                                           \
      for (int i_ = 0; i_ < 16; ++i_) {                                           \
        float cur_ = fmaf(x2[i_], p1[i_], -p2[i_]); p2[i_] = p1[i_]; p1[i_] = cur_; \
        unsigned short e_ = f2bf(cur_);                                           \
        if (i_ < 8) o0_.u[i_] = e_; else o1_.u[i_ - 8] = e_;                      \
      }                                                                           \
    }                                                                             \
    na0 = o0_.v; na1 = o1_.v; }

#define ISSUE_B(NS, BUF)                                                          \
  { const int k_ = (NS) % KP;                                                     \
    const int d0_ = kbase + ((NS) / KP) * 32;                                     \
    _Pragma("unroll")                                                             \
    for (int j_ = 0; j_ < 4; ++j_) {                                              \
      const short* g_ = wt + (size_t)k_ * 1048576 +                               \
                        (size_t)(colbase + bcol[j_]) * 1024 + d0_ + bgoff[j_];    \
      GLOAD_LDS16(g_, (char*)(&Bsm[BUF][0]) + (wid * 4 + j_) * 1024);             \
    } }

#define STAGE_B_F32(NS, BUF)                                                      \
  { const int k_ = (NS) % KP;                                                     \
    const int d0_ = kbase + ((NS) / KP) * 32;                                     \
    const int dd_ = tid & 31, cg_ = tid >> 5;                                     \
    const float* ws_ = w + (size_t)k_ * 1048576 + (size_t)(d0_ + dd_) * 1024 + colbase + cg_ * 4; \
    _Pragma("unroll")                                                             \
    for (int p_ = 0; p_ < 8; ++p_) {                                              \
      f32x4 f_ = *(const f32x4*)(ws_ + p_ * 32);                                  \
      _Pragma("unroll")                                                           \
      for (int jj_ = 0; jj_ < 4; ++jj_) {                                         \
        int col_ = cg_ * 4 + p_ * 32 + jj_;                                       \
        int byt_ = col_ * 64 + ((dd_ & 7) << 1) + ((((dd_ >> 3) ^ swz_e(col_)) & 3) << 4); \
        *(unsigned short*)((char*)(&Bsm[BUF][0]) + byt_) = f2bf(f_[jj_]);         \
      } } }

  // prologue: stage step 0 into buffer 0
  if constexpr (USE_WS) { ISSUE_B(0, 0); } else { STAGE_B_F32(0, 0); }
  GEN(0);
  *(s16x8*)((char*)(&Asm[0][0]) + aw0) = na0;
  *(s16x8*)((char*)(&Asm[0][0]) + aw1) = na1;
  __syncthreads();

  for (int step = 0; step < NSTEP; ++step) {
    const int cur = step & 1;
    if (step < NSTEP - 1) {
      if constexpr (USE_WS) { ISSUE_B(step + 1, cur ^ 1); } else { STAGE_B_F32(step + 1, cur ^ 1); }
      GEN(step + 1);
      *(s16x8*)((char*)(&Asm[cur ^ 1][0]) + aw0) = na0;
      *(s16x8*)((char*)(&Asm[cur ^ 1][0]) + aw1) = na1;
    }
    s16x8 af[4];
    #pragma unroll
    for (int m = 0; m < 4; ++m)
      af[m] = *(const s16x8*)((char*)(&Asm[cur][0]) + abyte[m]);
    __builtin_amdgcn_s_setprio(1);
    #pragma unroll
    for (int n = 0; n < 8; ++n) {
      s16x8 bfr = *(const s16x8*)((char*)(&Bsm[cur][0]) + bbyte[n]);
      #pragma unroll
      for (int m = 0; m < 4; ++m)
        acc[m][n] = __builtin_amdgcn_mfma_f32_16x16x32_bf16(af[m], bfr, acc[m][n], 0, 0, 0);
    }
    __builtin_amdgcn_s_setprio(0);
    __syncthreads();
  }

#undef GEN
#undef ISSUE_B
#undef STAGE_B_F32

  // epilogue: out += acc (split-K partial), hardware f32 atomics
  #pragma unroll
  for (int m = 0; m < 4; ++m) {
    const int r0 = rowbase + wr * 64 + m * 16 + lg * 4;
    #pragma unroll
    for (int n = 0; n < 8; ++n) {
      const int c = colbase + wc * 128 + n * 16 + la;
      #pragma unroll
      for (int j = 0; j < 4; ++j)
        unsafeAtomicAdd(&out[(size_t)(r0 + j) * 1024 + c], acc[m][n][j]);
    }
  }
}

extern "C" void kernel_launch(void* const* d_in, const int* in_sizes, int n_in,
                              void* d_out, int out_size, void* d_ws, size_t ws_size,
                              hipStream_t stream) {
  const float* x = (const float*)d_in[0];
  const float* w = (const float*)d_in[1];
  float* out = (float*)d_out;

  const size_t WT_BYTES = (size_t)8 * 1024 * 1024 * 2;   // 16 MiB: Wt[8][1024][1024] bf16
  const bool use_ws = ws_size >= WT_BYTES + 4096;

  if (use_ws) {
    short* wt   = (short*)d_ws;
    float* bias = (float*)((char*)d_ws + WT_BYTES);
    transpose_w<<<2048, 256, 0, stream>>>(w, wt);
    bias_k<<<16, 256, 0, stream>>>(w, bias);
    init_out<<<8192, 256, 0, stream>>>(bias, out, 1);
    cheb_gemm<true><<<512, 256, 0, stream>>>(x, w, wt, out);
  } else {
    init_out<<<8192, 256, 0, stream>>>(nullptr, out, 0);
    cheb_gemm<false><<<512, 256, 0, stream>>>(x, w, nullptr, out);
  }
}